// Round 3
// baseline (701.684 us; speedup 1.0000x reference)
//
#include <hip/hip_runtime.h>
#include <hip/hip_bf16.h>
#include <cstdint>

#define N_TOK 4096
#define DIM_  1024
#define HID_  4096
#define NEXP  8
#define HHALF 2048           // HID processed in two halves (h buffer reuse)
#define CAP   (3 * N_TOK)    // Sum n_e <= 3N (at most 3 gates can be >= 0.3)

typedef __attribute__((ext_vector_type(8))) short short8;
typedef __attribute__((ext_vector_type(4))) float f32x4;

__device__ __forceinline__ unsigned short f32_to_bf16(float f) {
    union { float f; uint32_t u; } v;
    v.f = f;
    uint32_t r = (v.u + 0x7fffu + ((v.u >> 16) & 1u)) >> 16;
    return (unsigned short)r;
}

__device__ __forceinline__ float gelu_exact(float x) {
    return 0.5f * x * (1.0f + erff(x * 0.70710678118654752440f));
}

__device__ __forceinline__ void gl_lds16(const unsigned short* g, unsigned short* l) {
    __builtin_amdgcn_global_load_lds(
        (const __attribute__((address_space(1))) void*)g,
        (__attribute__((address_space(3))) void*)l, 16, 0, 0);
}

// ---------------- zero-init fused output + per-expert counters ---------------
__global__ __launch_bounds__(256)
void zero_init_kernel(float* __restrict__ fused, int* __restrict__ cnt)
{
    const int b = blockIdx.x;
    if (b < N_TOK) {
        float4* p = (float4*)(fused + (size_t)b * DIM_);
        p[threadIdx.x] = make_float4(0.f, 0.f, 0.f, 0.f);
    } else if (threadIdx.x < NEXP) {
        cnt[threadIdx.x] = 0;
    }
}

// ---------------- Gate: one wave per row; softmax -> mask/renorm/fallback ----
__global__ __launch_bounds__(256)
void gate_kernel(const float* __restrict__ x, const float* __restrict__ wg,
                 const float* __restrict__ bg, float* __restrict__ gates,
                 float* __restrict__ wts, int* __restrict__ cnt)
{
    const int wave = threadIdx.x >> 6;
    const int lane = threadIdx.x & 63;
    const int n = blockIdx.x * 4 + wave;
    float acc[NEXP];
#pragma unroll
    for (int e = 0; e < NEXP; e++) acc[e] = 0.0f;
    const float4* xr = (const float4*)(x + (size_t)n * DIM_);
#pragma unroll
    for (int j = 0; j < 4; j++) {
        const int k4 = lane + j * 64;
        const float4 v = xr[k4];
        const float* wr = wg + (size_t)k4 * 4 * NEXP;
#pragma unroll
        for (int e = 0; e < NEXP; e++)
            acc[e] += v.x * wr[e] + v.y * wr[NEXP + e] +
                      v.z * wr[2 * NEXP + e] + v.w * wr[3 * NEXP + e];
    }
#pragma unroll
    for (int e = 0; e < NEXP; e++) {
#pragma unroll
        for (int off = 32; off > 0; off >>= 1)
            acc[e] += __shfl_xor(acc[e], off, 64);
    }
    if (lane == 0) {
        float z[NEXP];
#pragma unroll
        for (int e = 0; e < NEXP; e++) z[e] = acc[e] + bg[e];
        float m = z[0];
#pragma unroll
        for (int e = 1; e < NEXP; e++) m = fmaxf(m, z[e]);
        float p[NEXP], s = 0.0f;
#pragma unroll
        for (int e = 0; e < NEXP; e++) { p[e] = __expf(z[e] - m); s += p[e]; }
        const float invs = 1.0f / s;
        float g[NEXP];
        int top = 0;
#pragma unroll
        for (int e = 0; e < NEXP; e++) {
            g[e] = p[e] * invs;
            gates[(size_t)n * NEXP + e] = g[e];
            if (g[e] > g[top]) top = e;
        }
        float w[NEXP], sm = 0.0f;
        int c = 0;
#pragma unroll
        for (int e = 0; e < NEXP; e++) {
            const bool mk = (g[e] >= 0.3f);
            const float ms = mk ? g[e] : 0.0f;
            sm += ms; c += mk ? 1 : 0;
            w[e] = ms;
        }
        if (c == 0) {
#pragma unroll
            for (int e = 0; e < NEXP; e++) w[e] = 0.0f;
            w[top] = 1.0f;
        } else {
            const float inv = 1.0f / (sm + 1e-6f);
#pragma unroll
            for (int e = 0; e < NEXP; e++) w[e] *= inv;
        }
#pragma unroll
        for (int e = 0; e < NEXP; e++) {
            wts[(size_t)n * NEXP + e] = w[e];
            if (w[e] > 0.0f) atomicAdd(&cnt[e], 1);
        }
    }
}

// ---------------- offsets: exclusive prefix over cnt; zero cnt2 --------------
__global__ void offsets_kernel(const int* __restrict__ cnt, int* __restrict__ off,
                               int* __restrict__ cnt2)
{
    if (threadIdx.x == 0) {
        int a = 0;
        for (int e = 0; e < NEXP; e++) { off[e] = a; a += cnt[e]; cnt2[e] = 0; }
    }
}

// ---------------- build per-expert gathered row lists ------------------------
__global__ __launch_bounds__(256)
void build_list_kernel(const float* __restrict__ wts, const int* __restrict__ off,
                       int* __restrict__ cnt2, int* __restrict__ gidx,
                       float* __restrict__ wpk)
{
    const int n = blockIdx.x * 256 + threadIdx.x;
    if (n >= N_TOK) return;
#pragma unroll
    for (int e = 0; e < NEXP; e++) {
        const float w = wts[(size_t)n * NEXP + e];
        if (w > 0.0f) {
            const int slot = atomicAdd(&cnt2[e], 1);
            const int g = off[e] + slot;
            gidx[g] = n;
            wpk[g] = w;
        }
    }
}

// ---------------- gather rows of expert_inputs -> packed bf16 ----------------
__global__ __launch_bounds__(256)
void gather_cvt_kernel(const float* __restrict__ ei, const int* __restrict__ cnt,
                       const int* __restrict__ off, const int* __restrict__ gidx,
                       unsigned short* __restrict__ xg)
{
    const int e = blockIdx.y;
    const int ne = cnt[e];
    const int i0 = blockIdx.x * 8;
    if (i0 >= ne) return;
    const int grp = threadIdx.x >> 5;
    const int l32 = threadIdx.x & 31;
    const int i = i0 + grp;
    if (i >= ne) return;
    const int o = off[e];
    const float* src = ei + ((size_t)e * N_TOK + gidx[o + i]) * DIM_;
    unsigned short* dst = xg + (size_t)(o + i) * DIM_;
#pragma unroll
    for (int j = 0; j < 8; j++) {
        const int c = (l32 + j * 32) * 4;
        const float4 v = *(const float4*)(src + c);
        ushort4 u;
        u.x = f32_to_bf16(v.x); u.y = f32_to_bf16(v.y);
        u.z = f32_to_bf16(v.z); u.w = f32_to_bf16(v.w);
        *(ushort4*)(dst + c) = u;
    }
}

// ------- both weight transposes in one dispatch: fp32 [R][C] -> bf16 [C][R] --
// 4 tiles/block, all 16 global loads issued upfront (4x memory-level parallelism
// per thread -> latency paid once per 4 tiles). bf16 XOR-swizzled LDS, 16B stores.
__global__ __launch_bounds__(256)
void transpose_cvt3(const float* __restrict__ w1, const float* __restrict__ w2,
                    unsigned short* __restrict__ w1t, unsigned short* __restrict__ w2t)
{
    __shared__ __align__(16) unsigned short t[64 * 64];  // swizzled [c][r] bf16
    const int z = blockIdx.y;       // 0..7 -> w1 expert z; 8..15 -> w2 expert z-8
    const float* src;
    unsigned short* dst;
    int C, R, cmask, cshift;
    if (z < NEXP) {
        src = w1 + (size_t)z * DIM_ * HID_;
        dst = w1t + (size_t)z * DIM_ * HID_;
        C = HID_; R = DIM_; cmask = 63; cshift = 6;   // 64 cblk x 16 rblk
    } else {
        src = w2 + (size_t)(z - NEXP) * HID_ * DIM_;
        dst = w2t + (size_t)(z - NEXP) * HID_ * DIM_;
        C = DIM_; R = HID_; cmask = 15; cshift = 4;   // 16 cblk x 64 rblk
    }
    const int tid = threadIdx.x;
    const int rB = (tid >> 4) * 4;      // 0,4,...,60
    const int cB = (tid & 15) * 4;      // 0,4,...,60

    int c0[4], r0[4];
#pragma unroll
    for (int tt = 0; tt < 4; tt++) {
        const int id = blockIdx.x * 4 + tt;
        c0[tt] = (id & cmask) * 64;
        r0[tt] = (id >> cshift) * 64;
    }
    // Issue ALL loads first: 16 float4 in flight per thread.
    f32x4 rr[4][4];
#pragma unroll
    for (int tt = 0; tt < 4; tt++)
#pragma unroll
        for (int p = 0; p < 4; p++)
            rr[tt][p] = *(const f32x4*)(src + (size_t)(r0[tt] + rB + p) * C + c0[tt] + cB);

#pragma unroll
    for (int tt = 0; tt < 4; tt++) {
        if (tt) __syncthreads();        // LDS buffer reuse
        // Write transposed to LDS: for col c, ushort4 covering 4 consecutive rows.
        // Swizzle: 8-row block index XOR (c>>3)&7 -> conflict-free.
#pragma unroll
        for (int k = 0; k < 4; k++) {
            const int c = cB + k;
            const int s = (c >> 3) & 7;
            const int addr = c * 64 + (((rB >> 3) ^ s) << 3) + (rB & 7);
            ushort4 q;
            q.x = f32_to_bf16(rr[tt][0][k]);
            q.y = f32_to_bf16(rr[tt][1][k]);
            q.z = f32_to_bf16(rr[tt][2][k]);
            q.w = f32_to_bf16(rr[tt][3][k]);
            *(ushort4*)(t + addr) = q;
        }
        __syncthreads();
        // Store: 8 lanes emit one full 128B dst row as ushort8 each.
#pragma unroll
        for (int it2 = 0; it2 < 2; it2++) {
            const int c = (tid >> 3) + it2 * 32;
            const int g = tid & 7;
            const int s = (c >> 3) & 7;
            const short8 v8 = *(const short8*)(t + c * 64 + ((g ^ s) << 3));
            *(short8*)(dst + (size_t)(c0[tt] + c) * R + r0[tt] + g * 8) = v8;
        }
    }
}

// ---------------- GEMM1: h = gelu(Xg @ W1 + b1); 128x128 tile, batched -------
// Double-buffered LDS with counted vmcnt(4): next K-step's 4 global_load_lds
// stay in flight across the barrier (never drain to 0 in the main loop).
// grid: (HHALF/128, N_TOK/128, E); early-exit on gathered row count.
__global__ __launch_bounds__(256)
void gemm1_k(const unsigned short* __restrict__ xg, const unsigned short* __restrict__ w1t,
             const float* __restrict__ b1, unsigned short* __restrict__ hg,
             const int* __restrict__ cnt, const int* __restrict__ off, int h0)
{
    const int e = blockIdx.z;
    const int ne = cnt[e];
    const int rowBase = blockIdx.y * 128;
    if (rowBase >= ne) return;
    const int o = off[e];
    const int colBase = blockIdx.x * 128;

    __shared__ __align__(16) unsigned short sA[2][128 * 32];
    __shared__ __align__(16) unsigned short sB[2][128 * 32];
    const int tid  = threadIdx.x;
    const int lane = tid & 63;
    const int wave = tid >> 6;
    const int wr = wave >> 1, wc = wave & 1;   // 2x2 waves: 64 rows x 64 cols each

    f32x4 acc[4][4];
#pragma unroll
    for (int i = 0; i < 4; i++)
#pragma unroll
        for (int j = 0; j < 4; j++)
#pragma unroll
            for (int r = 0; r < 4; r++) acc[i][j][r] = 0.0f;

    const int sr = tid >> 2;            // 0..63
    const int sc = (tid & 3) << 3;
    const int rowA0 = min(rowBase + sr, ne - 1);
    const int rowA1 = min(rowBase + 64 + sr, ne - 1);
    const unsigned short* ga0 = xg + (size_t)(o + rowA0) * DIM_ + sc;
    const unsigned short* ga1 = xg + (size_t)(o + rowA1) * DIM_ + sc;
    const unsigned short* gb0 = w1t + ((size_t)e * HID_ + h0 + colBase + sr) * DIM_ + sc;
    const unsigned short* gb1 = gb0 + (size_t)64 * DIM_;

    const int aoff = (wr * 64 + (lane & 15)) * 32 + ((lane >> 4) << 3);
    const int boff = (wc * 64 + (lane & 15)) * 32 + ((lane >> 4) << 3);

    // prologue: stage K-step 0 into buffer 0
    gl_lds16(ga0, &sA[0][tid * 8]);
    gl_lds16(ga1, &sA[0][2048 + tid * 8]);
    gl_lds16(gb0, &sB[0][tid * 8]);
    gl_lds16(gb1, &sB[0][2048 + tid * 8]);

    const int NK = DIM_ / 32;
    for (int it = 0; it < NK; ++it) {
        const int cur = it & 1;
        const int nxt = cur ^ 1;
        // stage next K-step (redundant re-stage of last step into dead buffer)
        const int kn = (it + 1 < NK) ? (it + 1) * 32 : it * 32;
        gl_lds16(ga0 + kn, &sA[nxt][tid * 8]);
        gl_lds16(ga1 + kn, &sA[nxt][2048 + tid * 8]);
        gl_lds16(gb0 + kn, &sB[nxt][tid * 8]);
        gl_lds16(gb1 + kn, &sB[nxt][2048 + tid * 8]);
        // wait only for cur's 4 loads; nxt's 4 remain in flight across barrier
        asm volatile("s_waitcnt vmcnt(4)\n\ts_barrier" ::: "memory");
        short8 av[4], bv[4];
#pragma unroll
        for (int i = 0; i < 4; i++) av[i] = *(const short8*)(&sA[cur][aoff + i * 16 * 32]);
#pragma unroll
        for (int j = 0; j < 4; j++) bv[j] = *(const short8*)(&sB[cur][boff + j * 16 * 32]);
#pragma unroll
        for (int i = 0; i < 4; i++)
#pragma unroll
            for (int j = 0; j < 4; j++)
                acc[i][j] = __builtin_amdgcn_mfma_f32_16x16x32_bf16(av[i], bv[j], acc[i][j], 0, 0, 0);
        // all waves done reading cur before next iter overwrites it
        asm volatile("s_barrier" ::: "memory");
    }

    const int crow = rowBase + wr * 64 + ((lane >> 4) << 2);
    const int ccol = colBase + wc * 64 + (lane & 15);
#pragma unroll
    for (int i = 0; i < 4; i++) {
#pragma unroll
        for (int j = 0; j < 4; j++) {
            const int col = ccol + j * 16;
            const float b = b1[(size_t)e * HID_ + h0 + col];
#pragma unroll
            for (int r = 0; r < 4; r++) {
                const int row = crow + i * 16 + r;
                if (row < ne) {
                    const float v = acc[i][j][r] + b;
                    hg[(size_t)(o + row) * HHALF + col] = f32_to_bf16(gelu_exact(v));
                }
            }
        }
    }
}

// -------- GEMM2: fused[gidx[r]] += w * (Hg @ W2 + b2); 128x128 tile, split-K=2
// Same double-buffered counted-vmcnt K-loop. grid: (16, N_TOK/128, E).
__global__ __launch_bounds__(256)
void gemm2_k(const unsigned short* __restrict__ hg, const unsigned short* __restrict__ w2t,
             const float* __restrict__ b2, float* __restrict__ fused,
             const int* __restrict__ cnt, const int* __restrict__ off,
             const int* __restrict__ gidx, const float* __restrict__ wpk, int h0)
{
    const int e = blockIdx.z;
    const int ne = cnt[e];
    const int rowBase = blockIdx.y * 128;
    if (rowBase >= ne) return;
    const int o = off[e];
    const int colBase = (blockIdx.x & 7) * 128;
    const int kc = blockIdx.x >> 3;            // 0,1 : K chunk of 1024 within HHALF
    const int kbeg = kc * (HHALF / 2);

    __shared__ __align__(16) unsigned short sA[2][128 * 32];
    __shared__ __align__(16) unsigned short sB[2][128 * 32];
    const int tid  = threadIdx.x;
    const int lane = tid & 63;
    const int wave = tid >> 6;
    const int wr = wave >> 1, wc = wave & 1;

    f32x4 acc[4][4];
#pragma unroll
    for (int i = 0; i < 4; i++)
#pragma unroll
        for (int j = 0; j < 4; j++)
#pragma unroll
            for (int r = 0; r < 4; r++) acc[i][j][r] = 0.0f;

    const int sr = tid >> 2;
    const int sc = (tid & 3) << 3;
    const int rowA0 = min(rowBase + sr, ne - 1);
    const int rowA1 = min(rowBase + 64 + sr, ne - 1);
    const unsigned short* ga0 = hg + (size_t)(o + rowA0) * HHALF + kbeg + sc;
    const unsigned short* ga1 = hg + (size_t)(o + rowA1) * HHALF + kbeg + sc;
    const unsigned short* gb0 = w2t + ((size_t)e * DIM_ + colBase + sr) * HID_ + h0 + kbeg + sc;
    const unsigned short* gb1 = gb0 + (size_t)64 * HID_;

    const int aoff = (wr * 64 + (lane & 15)) * 32 + ((lane >> 4) << 3);
    const int boff = (wc * 64 + (lane & 15)) * 32 + ((lane >> 4) << 3);

    gl_lds16(ga0, &sA[0][tid * 8]);
    gl_lds16(ga1, &sA[0][2048 + tid * 8]);
    gl_lds16(gb0, &sB[0][tid * 8]);
    gl_lds16(gb1, &sB[0][2048 + tid * 8]);

    const int NK = (HHALF / 2) / 32;
    for (int it = 0; it < NK; ++it) {
        const int cur = it & 1;
        const int nxt = cur ^ 1;
        const int kn = (it + 1 < NK) ? (it + 1) * 32 : it * 32;
        gl_lds16(ga0 + kn, &sA[nxt][tid * 8]);
        gl_lds16(ga1 + kn, &sA[nxt][2048 + tid * 8]);
        gl_lds16(gb0 + kn, &sB[nxt][tid * 8]);
        gl_lds16(gb1 + kn, &sB[nxt][2048 + tid * 8]);
        asm volatile("s_waitcnt vmcnt(4)\n\ts_barrier" ::: "memory");
        short8 av[4], bv[4];
#pragma unroll
        for (int i = 0; i < 4; i++) av[i] = *(const short8*)(&sA[cur][aoff + i * 16 * 32]);
#pragma unroll
        for (int j = 0; j < 4; j++) bv[j] = *(const short8*)(&sB[cur][boff + j * 16 * 32]);
#pragma unroll
        for (int i = 0; i < 4; i++)
#pragma unroll
            for (int j = 0; j < 4; j++)
                acc[i][j] = __builtin_amdgcn_mfma_f32_16x16x32_bf16(av[i], bv[j], acc[i][j], 0, 0, 0);
        asm volatile("s_barrier" ::: "memory");
    }

    const int crow = rowBase + wr * 64 + ((lane >> 4) << 2);
    const int ccol = colBase + wc * 64 + (lane & 15);
    const int addBias = (h0 == 0 && kc == 0);
#pragma unroll
    for (int i = 0; i < 4; i++) {
#pragma unroll
        for (int j = 0; j < 4; j++) {
            const int col = ccol + j * 16;
            const float b = addBias ? b2[(size_t)e * DIM_ + col] : 0.0f;
#pragma unroll
            for (int r = 0; r < 4; r++) {
                const int row = crow + i * 16 + r;
                if (row < ne) {
                    const float w = wpk[o + row];
                    const int orow = gidx[o + row];
                    atomicAdd(&fused[(size_t)orow * DIM_ + col], w * (acc[i][j][r] + b));
                }
            }
        }
    }
}

extern "C" void kernel_launch(void* const* d_in, const int* in_sizes, int n_in,
                              void* d_out, int out_size, void* d_ws, size_t ws_size,
                              hipStream_t stream)
{
    const float* x  = (const float*)d_in[0];
    const float* ei = (const float*)d_in[1];
    const float* wg = (const float*)d_in[2];
    const float* bg = (const float*)d_in[3];
    const float* w1 = (const float*)d_in[4];
    const float* b1 = (const float*)d_in[5];
    const float* w2 = (const float*)d_in[6];
    const float* b2 = (const float*)d_in[7];

    float* fused = (float*)d_out;                    // [N, DIM]
    float* gates = fused + (size_t)N_TOK * DIM_;     // [N, E]

    // workspace (~210 MB; 235 MB proven safe in round 1)
    unsigned short* xg  = (unsigned short*)d_ws;                   // [CAP][DIM] bf16
    unsigned short* hg  = xg  + (size_t)CAP * DIM_;                // [CAP][HHALF] bf16
    unsigned short* w1t = hg  + (size_t)CAP * HHALF;               // [E][HID][DIM]
    unsigned short* w2t = w1t + (size_t)NEXP * HID_ * DIM_;        // [E][DIM][HID]
    float* wts = (float*)(w2t + (size_t)NEXP * DIM_ * HID_);       // [N][E]
    float* wpk = wts + (size_t)N_TOK * NEXP;                       // [CAP]
    int* gidx  = (int*)(wpk + CAP);                                // [CAP]
    int* cnt   = gidx + CAP;                                       // [E]
    int* off   = cnt + NEXP;                                       // [E]
    int* cnt2  = off + NEXP;                                       // [E]

    zero_init_kernel<<<N_TOK + 1, 256, 0, stream>>>(fused, cnt);
    gate_kernel<<<N_TOK / 4, 256, 0, stream>>>(x, wg, bg, gates, wts, cnt);
    offsets_kernel<<<1, 64, 0, stream>>>(cnt, off, cnt2);
    build_list_kernel<<<N_TOK / 256, 256, 0, stream>>>(wts, off, cnt2, gidx, wpk);

    gather_cvt_kernel<<<dim3(N_TOK / 8, NEXP), 256, 0, stream>>>(ei, cnt, off, gidx, xg);
    transpose_cvt3<<<dim3(256, 16), 256, 0, stream>>>(w1, w2, w1t, w2t);

    for (int h0 = 0; h0 < HID_; h0 += HHALF) {
        gemm1_k<<<dim3(HHALF / 128, N_TOK / 128, NEXP), 256, 0, stream>>>(
            xg, w1t, b1, hg, cnt, off, h0);
        gemm2_k<<<dim3(16, N_TOK / 128, NEXP), 256, 0, stream>>>(
            hg, w2t, b2, fused, cnt, off, gidx, wpk, h0);
    }
}

// Round 4
// 626.760 us; speedup vs baseline: 1.1195x; 1.1195x over previous
//
#include <hip/hip_runtime.h>
#include <hip/hip_bf16.h>
#include <cstdint>

#define N_TOK 4096
#define DIM_  1024
#define HID_  4096
#define NEXP  8
#define HHALF 2048           // HID processed in two halves (h buffer reuse)
#define CAP   (3 * N_TOK)    // Sum n_e <= 3N (at most 3 gates can be >= 0.3)

typedef __attribute__((ext_vector_type(8))) short short8;
typedef __attribute__((ext_vector_type(4))) float f32x4;

__device__ __forceinline__ unsigned short f32_to_bf16(float f) {
    union { float f; uint32_t u; } v;
    v.f = f;
    uint32_t r = (v.u + 0x7fffu + ((v.u >> 16) & 1u)) >> 16;
    return (unsigned short)r;
}

__device__ __forceinline__ float gelu_exact(float x) {
    return 0.5f * x * (1.0f + erff(x * 0.70710678118654752440f));
}

__device__ __forceinline__ void gl_lds16(const unsigned short* g, unsigned short* l) {
    __builtin_amdgcn_global_load_lds(
        (const __attribute__((address_space(1))) void*)g,
        (__attribute__((address_space(3))) void*)l, 16, 0, 0);
}

// ---- Gate: one wave per row; softmax -> mask/renorm/fallback.
//      Also zeroes this block's 4 rows of fused (folds old zero_init_kernel).
__global__ __launch_bounds__(256)
void gate_kernel(const float* __restrict__ x, const float* __restrict__ wg,
                 const float* __restrict__ bg, float* __restrict__ gates,
                 float* __restrict__ wts, int* __restrict__ cnt,
                 float* __restrict__ fused)
{
    // zero 4 rows of fused owned by this block
    {
        float4* fz = (float4*)(fused + (size_t)blockIdx.x * 4 * DIM_);
#pragma unroll
        for (int i = 0; i < 4; i++)
            fz[i * 256 + threadIdx.x] = make_float4(0.f, 0.f, 0.f, 0.f);
    }
    const int wave = threadIdx.x >> 6;
    const int lane = threadIdx.x & 63;
    const int n = blockIdx.x * 4 + wave;
    float acc[NEXP];
#pragma unroll
    for (int e = 0; e < NEXP; e++) acc[e] = 0.0f;
    const f32x4* xr = (const f32x4*)(x + (size_t)n * DIM_);
#pragma unroll
    for (int j = 0; j < 4; j++) {
        const int k4 = lane + j * 64;
        const f32x4 v = __builtin_nontemporal_load(xr + k4);   // x read once
        const float* wr = wg + (size_t)k4 * 4 * NEXP;
#pragma unroll
        for (int e = 0; e < NEXP; e++)
            acc[e] += v[0] * wr[e] + v[1] * wr[NEXP + e] +
                      v[2] * wr[2 * NEXP + e] + v[3] * wr[3 * NEXP + e];
    }
#pragma unroll
    for (int e = 0; e < NEXP; e++) {
#pragma unroll
        for (int off = 32; off > 0; off >>= 1)
            acc[e] += __shfl_xor(acc[e], off, 64);
    }
    if (lane == 0) {
        float z[NEXP];
#pragma unroll
        for (int e = 0; e < NEXP; e++) z[e] = acc[e] + bg[e];
        float m = z[0];
#pragma unroll
        for (int e = 1; e < NEXP; e++) m = fmaxf(m, z[e]);
        float p[NEXP], s = 0.0f;
#pragma unroll
        for (int e = 0; e < NEXP; e++) { p[e] = __expf(z[e] - m); s += p[e]; }
        const float invs = 1.0f / s;
        float g[NEXP];
        int top = 0;
#pragma unroll
        for (int e = 0; e < NEXP; e++) {
            g[e] = p[e] * invs;
            gates[(size_t)n * NEXP + e] = g[e];
            if (g[e] > g[top]) top = e;
        }
        float w[NEXP], sm = 0.0f;
        int c = 0;
#pragma unroll
        for (int e = 0; e < NEXP; e++) {
            const bool mk = (g[e] >= 0.3f);
            const float ms = mk ? g[e] : 0.0f;
            sm += ms; c += mk ? 1 : 0;
            w[e] = ms;
        }
        if (c == 0) {
#pragma unroll
            for (int e = 0; e < NEXP; e++) w[e] = 0.0f;
            w[top] = 1.0f;
        } else {
            const float inv = 1.0f / (sm + 1e-6f);
#pragma unroll
            for (int e = 0; e < NEXP; e++) w[e] *= inv;
        }
#pragma unroll
        for (int e = 0; e < NEXP; e++) {
            wts[(size_t)n * NEXP + e] = w[e];
            if (w[e] > 0.0f) atomicAdd(&cnt[e], 1);
        }
    }
}

// ---- build per-expert gathered row lists; folds offsets_kernel (local prefix;
//      block 0 publishes off[] for downstream kernels). cnt2 pre-zeroed by memset.
__global__ __launch_bounds__(256)
void build_list_kernel(const float* __restrict__ wts, const int* __restrict__ cnt,
                       int* __restrict__ off, int* __restrict__ cnt2,
                       int* __restrict__ gidx, float* __restrict__ wpk)
{
    int pre[NEXP];
    {
        int a = 0;
#pragma unroll
        for (int e = 0; e < NEXP; e++) { pre[e] = a; a += cnt[e]; }
    }
    if (blockIdx.x == 0 && threadIdx.x == 0) {
#pragma unroll
        for (int e = 0; e < NEXP; e++) off[e] = pre[e];
    }
    const int n = blockIdx.x * 256 + threadIdx.x;
    if (n >= N_TOK) return;
#pragma unroll
    for (int e = 0; e < NEXP; e++) {
        const float w = wts[(size_t)n * NEXP + e];
        if (w > 0.0f) {
            const int slot = atomicAdd(&cnt2[e], 1);
            const int g = pre[e] + slot;
            gidx[g] = n;
            wpk[g] = w;
        }
    }
}

// ---------------- gather rows of expert_inputs -> packed bf16 ----------------
__global__ __launch_bounds__(256)
void gather_cvt_kernel(const float* __restrict__ ei, const int* __restrict__ cnt,
                       const int* __restrict__ off, const int* __restrict__ gidx,
                       unsigned short* __restrict__ xg)
{
    const int e = blockIdx.y;
    const int ne = cnt[e];
    const int i0 = blockIdx.x * 8;
    if (i0 >= ne) return;
    const int grp = threadIdx.x >> 5;
    const int l32 = threadIdx.x & 31;
    const int i = i0 + grp;
    if (i >= ne) return;
    const int o = off[e];
    const float* src = ei + ((size_t)e * N_TOK + gidx[o + i]) * DIM_;
    unsigned short* dst = xg + (size_t)(o + i) * DIM_;
#pragma unroll
    for (int j = 0; j < 8; j++) {
        const int c = l32 + j * 32;
        const f32x4 v = __builtin_nontemporal_load((const f32x4*)src + c); // ei read once
        ushort4 u;
        u.x = f32_to_bf16(v[0]); u.y = f32_to_bf16(v[1]);
        u.z = f32_to_bf16(v[2]); u.w = f32_to_bf16(v[3]);
        *(ushort4*)(dst + c * 4) = u;
    }
}

// ------- both weight transposes in one dispatch: fp32 [R][C] -> bf16 [C][R] --
// NT loads (w1/w2 read exactly once -> bypass L2/L3, keep L3 for w1t/w2t which
// the GEMMs re-read ~5x). bf16 XOR-swizzled LDS, 16B stores.
__global__ __launch_bounds__(256)
void transpose_cvt3(const float* __restrict__ w1, const float* __restrict__ w2,
                    unsigned short* __restrict__ w1t, unsigned short* __restrict__ w2t)
{
    __shared__ __align__(16) unsigned short t[64 * 64];  // swizzled [c][r] bf16
    const int z = blockIdx.y;       // 0..7 -> w1 expert z; 8..15 -> w2 expert z-8
    const float* src;
    unsigned short* dst;
    int C, R, cb, rb;
    if (z < NEXP) {
        src = w1 + (size_t)z * DIM_ * HID_;
        dst = w1t + (size_t)z * DIM_ * HID_;
        C = HID_; R = DIM_;
        cb = blockIdx.x & 63; rb = blockIdx.x >> 6;   // 64 cblk x 16 rblk
    } else {
        src = w2 + (size_t)(z - NEXP) * HID_ * DIM_;
        dst = w2t + (size_t)(z - NEXP) * HID_ * DIM_;
        C = DIM_; R = HID_;
        cb = blockIdx.x & 15; rb = blockIdx.x >> 4;   // 16 cblk x 64 rblk
    }
    const int c0 = cb * 64, r0 = rb * 64;
    const int tid = threadIdx.x;

    const int rB = (tid >> 4) * 4;      // 0,4,...,60
    const int cB = (tid & 15) * 4;      // 0,4,...,60
    f32x4 vv[4];
#pragma unroll
    for (int p = 0; p < 4; p++)
        vv[p] = __builtin_nontemporal_load(
            (const f32x4*)(src + (size_t)(r0 + rB + p) * C + c0 + cB));
#pragma unroll
    for (int k = 0; k < 4; k++) {
        const int c = cB + k;
        const int s = (c >> 3) & 7;
        const int addr = c * 64 + (((rB >> 3) ^ s) << 3) + (rB & 7);
        ushort4 q;
        q.x = f32_to_bf16(vv[0][k]);
        q.y = f32_to_bf16(vv[1][k]);
        q.z = f32_to_bf16(vv[2][k]);
        q.w = f32_to_bf16(vv[3][k]);
        *(ushort4*)(t + addr) = q;
    }
    __syncthreads();
#pragma unroll
    for (int it = 0; it < 2; it++) {
        const int c = (tid >> 3) + it * 32;
        const int g = tid & 7;
        const int s = (c >> 3) & 7;
        const short8 v8 = *(const short8*)(t + c * 64 + ((g ^ s) << 3));
        *(short8*)(dst + (size_t)(c0 + c) * R + r0 + g * 8) = v8;
    }
}

// ---------------- GEMM1: h = gelu(Xg @ W1 + b1); 128x128 tile, batched -------
// grid: (HHALF/128, N_TOK/128, E); early-exit on gathered row count.
__global__ __launch_bounds__(256)
void gemm1_k(const unsigned short* __restrict__ xg, const unsigned short* __restrict__ w1t,
             const float* __restrict__ b1, unsigned short* __restrict__ hg,
             const int* __restrict__ cnt, const int* __restrict__ off, int h0)
{
    const int e = blockIdx.z;
    const int ne = cnt[e];
    const int rowBase = blockIdx.y * 128;
    if (rowBase >= ne) return;
    const int o = off[e];
    const int colBase = blockIdx.x * 128;

    __shared__ __align__(16) unsigned short sA[128 * 32];
    __shared__ __align__(16) unsigned short sB[128 * 32];
    const int tid  = threadIdx.x;
    const int lane = tid & 63;
    const int wave = tid >> 6;
    const int wr = wave >> 1, wc = wave & 1;   // 2x2 waves: 64 rows x 64 cols each

    f32x4 acc[4][4];
#pragma unroll
    for (int i = 0; i < 4; i++)
#pragma unroll
        for (int j = 0; j < 4; j++)
#pragma unroll
            for (int r = 0; r < 4; r++) acc[i][j][r] = 0.0f;

    const int sr = tid >> 2;            // 0..63
    const int sc = (tid & 3) << 3;
    const int rowA0 = min(rowBase + sr, ne - 1);
    const int rowA1 = min(rowBase + 64 + sr, ne - 1);
    const unsigned short* ga0 = xg + (size_t)(o + rowA0) * DIM_ + sc;
    const unsigned short* ga1 = xg + (size_t)(o + rowA1) * DIM_ + sc;
    const unsigned short* gb0 = w1t + ((size_t)e * HID_ + h0 + colBase + sr) * DIM_ + sc;
    const unsigned short* gb1 = gb0 + (size_t)64 * DIM_;
    unsigned short* la0 = sA + tid * 8;
    unsigned short* la1 = sA + 2048 + tid * 8;
    unsigned short* lb0 = sB + tid * 8;
    unsigned short* lb1 = sB + 2048 + tid * 8;

    const int aoff = (wr * 64 + (lane & 15)) * 32 + ((lane >> 4) << 3);
    const int boff = (wc * 64 + (lane & 15)) * 32 + ((lane >> 4) << 3);

    for (int k0 = 0; k0 < DIM_; k0 += 32) {
        gl_lds16(ga0 + k0, la0);
        gl_lds16(ga1 + k0, la1);
        gl_lds16(gb0 + k0, lb0);
        gl_lds16(gb1 + k0, lb1);
        __syncthreads();
        short8 av[4], bv[4];
#pragma unroll
        for (int i = 0; i < 4; i++) av[i] = *(const short8*)(sA + aoff + i * 16 * 32);
#pragma unroll
        for (int j = 0; j < 4; j++) bv[j] = *(const short8*)(sB + boff + j * 16 * 32);
#pragma unroll
        for (int i = 0; i < 4; i++)
#pragma unroll
            for (int j = 0; j < 4; j++)
                acc[i][j] = __builtin_amdgcn_mfma_f32_16x16x32_bf16(av[i], bv[j], acc[i][j], 0, 0, 0);
        __syncthreads();
    }

    const int crow = rowBase + wr * 64 + ((lane >> 4) << 2);
    const int ccol = colBase + wc * 64 + (lane & 15);
#pragma unroll
    for (int i = 0; i < 4; i++) {
#pragma unroll
        for (int j = 0; j < 4; j++) {
            const int col = ccol + j * 16;
            const float b = b1[(size_t)e * HID_ + h0 + col];
#pragma unroll
            for (int r = 0; r < 4; r++) {
                const int row = crow + i * 16 + r;
                if (row < ne) {
                    const float v = acc[i][j][r] + b;
                    hg[(size_t)(o + row) * HHALF + col] = f32_to_bf16(gelu_exact(v));
                }
            }
        }
    }
}

// -------- GEMM2: fused[gidx[r]] += w * (Hg @ W2 + b2); 128x128 tile, split-K=2
// grid: (16 = 8 colBlk x 2 kChunk, N_TOK/128, E).
__global__ __launch_bounds__(256)
void gemm2_k(const unsigned short* __restrict__ hg, const unsigned short* __restrict__ w2t,
             const float* __restrict__ b2, float* __restrict__ fused,
             const int* __restrict__ cnt, const int* __restrict__ off,
             const int* __restrict__ gidx, const float* __restrict__ wpk, int h0)
{
    const int e = blockIdx.z;
    const int ne = cnt[e];
    const int rowBase = blockIdx.y * 128;
    if (rowBase >= ne) return;
    const int o = off[e];
    const int colBase = (blockIdx.x & 7) * 128;
    const int kc = blockIdx.x >> 3;            // 0,1 : K chunk of 1024 within HHALF
    const int kbeg = kc * (HHALF / 2);

    __shared__ __align__(16) unsigned short sA[128 * 32];
    __shared__ __align__(16) unsigned short sB[128 * 32];
    const int tid  = threadIdx.x;
    const int lane = tid & 63;
    const int wave = tid >> 6;
    const int wr = wave >> 1, wc = wave & 1;

    f32x4 acc[4][4];
#pragma unroll
    for (int i = 0; i < 4; i++)
#pragma unroll
        for (int j = 0; j < 4; j++)
#pragma unroll
            for (int r = 0; r < 4; r++) acc[i][j][r] = 0.0f;

    const int sr = tid >> 2;
    const int sc = (tid & 3) << 3;
    const int rowA0 = min(rowBase + sr, ne - 1);
    const int rowA1 = min(rowBase + 64 + sr, ne - 1);
    const unsigned short* ga0 = hg + (size_t)(o + rowA0) * HHALF + kbeg + sc;
    const unsigned short* ga1 = hg + (size_t)(o + rowA1) * HHALF + kbeg + sc;
    const unsigned short* gb0 = w2t + ((size_t)e * DIM_ + colBase + sr) * HID_ + h0 + kbeg + sc;
    const unsigned short* gb1 = gb0 + (size_t)64 * HID_;
    unsigned short* la0 = sA + tid * 8;
    unsigned short* la1 = sA + 2048 + tid * 8;
    unsigned short* lb0 = sB + tid * 8;
    unsigned short* lb1 = sB + 2048 + tid * 8;

    const int aoff = (wr * 64 + (lane & 15)) * 32 + ((lane >> 4) << 3);
    const int boff = (wc * 64 + (lane & 15)) * 32 + ((lane >> 4) << 3);

    for (int k0 = 0; k0 < HHALF / 2; k0 += 32) {
        gl_lds16(ga0 + k0, la0);
        gl_lds16(ga1 + k0, la1);
        gl_lds16(gb0 + k0, lb0);
        gl_lds16(gb1 + k0, lb1);
        __syncthreads();
        short8 av[4], bv[4];
#pragma unroll
        for (int i = 0; i < 4; i++) av[i] = *(const short8*)(sA + aoff + i * 16 * 32);
#pragma unroll
        for (int j = 0; j < 4; j++) bv[j] = *(const short8*)(sB + boff + j * 16 * 32);
#pragma unroll
        for (int i = 0; i < 4; i++)
#pragma unroll
            for (int j = 0; j < 4; j++)
                acc[i][j] = __builtin_amdgcn_mfma_f32_16x16x32_bf16(av[i], bv[j], acc[i][j], 0, 0, 0);
        __syncthreads();
    }

    const int crow = rowBase + wr * 64 + ((lane >> 4) << 2);
    const int ccol = colBase + wc * 64 + (lane & 15);
    const int addBias = (h0 == 0 && kc == 0);
#pragma unroll
    for (int i = 0; i < 4; i++) {
#pragma unroll
        for (int j = 0; j < 4; j++) {
            const int col = ccol + j * 16;
            const float b = addBias ? b2[(size_t)e * DIM_ + col] : 0.0f;
#pragma unroll
            for (int r = 0; r < 4; r++) {
                const int row = crow + i * 16 + r;
                if (row < ne) {
                    const float w = wpk[o + row];
                    const int orow = gidx[o + row];
                    atomicAdd(&fused[(size_t)orow * DIM_ + col], w * (acc[i][j][r] + b));
                }
            }
        }
    }
}

extern "C" void kernel_launch(void* const* d_in, const int* in_sizes, int n_in,
                              void* d_out, int out_size, void* d_ws, size_t ws_size,
                              hipStream_t stream)
{
    const float* x  = (const float*)d_in[0];
    const float* ei = (const float*)d_in[1];
    const float* wg = (const float*)d_in[2];
    const float* bg = (const float*)d_in[3];
    const float* w1 = (const float*)d_in[4];
    const float* b1 = (const float*)d_in[5];
    const float* w2 = (const float*)d_in[6];
    const float* b2 = (const float*)d_in[7];

    float* fused = (float*)d_out;                    // [N, DIM]
    float* gates = fused + (size_t)N_TOK * DIM_;     // [N, E]

    // workspace (~210 MB; 235 MB proven safe in round 1)
    unsigned short* xg  = (unsigned short*)d_ws;                   // [CAP][DIM] bf16
    unsigned short* hg  = xg  + (size_t)CAP * DIM_;                // [CAP][HHALF] bf16
    unsigned short* w1t = hg  + (size_t)CAP * HHALF;               // [E][HID][DIM]
    unsigned short* w2t = w1t + (size_t)NEXP * HID_ * DIM_;        // [E][DIM][HID]
    float* wts = (float*)(w2t + (size_t)NEXP * DIM_ * HID_);       // [N][E]
    float* wpk = wts + (size_t)N_TOK * NEXP;                       // [CAP]
    int* gidx  = (int*)(wpk + CAP);                                // [CAP]
    int* cnt   = gidx + CAP;                                       // [E]
    int* off   = cnt + NEXP;                                       // [E]
    int* cnt2  = off + NEXP;                                       // [E]

    // zero cnt/off/cnt2 in one shot (contiguous)
    hipMemsetAsync(cnt, 0, 3 * NEXP * sizeof(int), stream);

    gate_kernel<<<N_TOK / 4, 256, 0, stream>>>(x, wg, bg, gates, wts, cnt, fused);
    build_list_kernel<<<N_TOK / 256, 256, 0, stream>>>(wts, cnt, off, cnt2, gidx, wpk);

    gather_cvt_kernel<<<dim3(N_TOK / 8, NEXP), 256, 0, stream>>>(ei, cnt, off, gidx, xg);
    transpose_cvt3<<<dim3(1024, 16), 256, 0, stream>>>(w1, w2, w1t, w2t);

    for (int h0 = 0; h0 < HID_; h0 += HHALF) {
        gemm1_k<<<dim3(HHALF / 128, N_TOK / 128, NEXP), 256, 0, stream>>>(
            xg, w1t, b1, hg, cnt, off, h0);
        gemm2_k<<<dim3(16, N_TOK / 128, NEXP), 256, 0, stream>>>(
            hg, w2t, b2, fused, cnt, off, gidx, wpk, h0);
    }
}